// Round 5
// baseline (2695.304 us; speedup 1.0000x reference)
//
#include <hip/hip_runtime.h>
#include <hip/hip_bf16.h>

#define BATCH 4
#define T 64000
#define C 128
#define NCLS 256
#define NLAYER 28

typedef __attribute__((ext_vector_type(8))) short short8;
typedef __attribute__((ext_vector_type(4))) float f32x4;
typedef unsigned short u16;

static __device__ __forceinline__ u16 f2bf(float x) {
    __hip_bfloat16 h = __float2bfloat16(x);
    return *reinterpret_cast<u16*>(&h);
}

// ---------------------------------------------------------------------------
// Weight prep: convert w_rest -> Wt[l][o][k] bf16 (k = tap*128 + i, tap0 = past)
// and w_cls -> Wc[o][k] bf16.
// ---------------------------------------------------------------------------
__global__ void prep_weights(const float* __restrict__ w_rest,
                             const float* __restrict__ w_cls,
                             u16* __restrict__ Wt, u16* __restrict__ Wc)
{
    const size_t n1 = (size_t)27 * 128 * 256;   // 884736
    const size_t n2 = (size_t)NCLS * C;         // 32768
    for (size_t idx = (size_t)blockIdx.x * 256 + threadIdx.x; idx < n1 + n2;
         idx += (size_t)gridDim.x * 256) {
        if (idx < n1) {
            const int k   = (int)(idx & 255);
            const int o   = (int)((idx >> 8) & 127);
            const int l   = (int)(idx >> 15);
            const int tap = k >> 7;
            const int i   = k & 127;
            Wt[idx] = f2bf(w_rest[(((size_t)l * 128 + o) * 128 + i) * 2 + tap]);
        } else {
            const size_t j = idx - n1;
            Wc[j] = f2bf(w_cls[j]);
        }
    }
}

// ---------------------------------------------------------------------------
// Layer 0: 1 channel -> 128 channels, d=1.  x[b][t][c] bf16 output.
// 64 t-rows per block.
// ---------------------------------------------------------------------------
__global__ void first_layer(const float* __restrict__ seq,
                            u16* __restrict__ xout,
                            const float* __restrict__ wf)
{
    __shared__ float w0[C], w1[C];
    const int tid = threadIdx.x;
    if (tid < C) { w0[tid] = wf[tid * 2]; w1[tid] = wf[tid * 2 + 1]; }
    __syncthreads();

    const int b  = blockIdx.y;
    const int og = tid & 15;
#pragma unroll
    for (int tt = 0; tt < 4; ++tt) {
        const int t = blockIdx.x * 64 + tt * 16 + (tid >> 4);
        const float s1 = seq[(size_t)b * T + t];
        const float s0 = (t > 0) ? seq[(size_t)b * T + t - 1] : 0.f;
        short8 v = {};
#pragma unroll
        for (int k = 0; k < 8; ++k) {
            const int o = og * 8 + k;
            float y = fmaf(w0[o], s0, w1[o] * s1);
            y = y > 0.f ? y : 0.f;
            v[k] = (short)f2bf(y);
        }
        *reinterpret_cast<short8*>(xout + ((size_t)b * T + t) * C + og * 8) = v;
    }
}

// ---------------------------------------------------------------------------
// Dilated conv layer (128->128, kernel 2, dilation d) as MFMA GEMM.
// D[t][o] = relu( sum_k A[t][k] * W[o][k] ),  k = tap*128 + ch, tap0 -> t-d.
// Block: 512 thr = 8 waves (4 t-quarters x 2 o-halves). Tile 128t x 128o,
// 4 tiles per block (512 t-rows).  Weights in LDS, XOR-swizzled.
// 64 KiB LDS -> 2 blocks/CU -> 16 waves/CU (4 waves/SIMD).
// ---------------------------------------------------------------------------
__global__ __launch_bounds__(512, 4) void conv_layer(
    const u16* __restrict__ xin, u16* __restrict__ xout,
    const u16* __restrict__ Wt, int d)
{
    __shared__ u16 wlds[C * 256];   // 64 KiB
    const int tid = threadIdx.x;
#pragma unroll
    for (int c = 0; c < 8; ++c) {
        const int cc = c * 512 + tid;       // 4096 chunks of 16B
        const int o = cc >> 5, kc = cc & 31;
        short8 v = *reinterpret_cast<const short8*>(Wt + o * 256 + kc * 8);
        *reinterpret_cast<short8*>(&wlds[o * 256 + ((kc * 8) ^ ((o & 7) << 3))]) = v;
    }
    __syncthreads();

    const int b    = blockIdx.y;
    const int wv   = tid >> 6, lane = tid & 63;
    const int wr   = wv >> 1, wc = wv & 1;      // wr: t-quarter, wc: o-half
    const int l15  = lane & 15, l4 = lane >> 4;
    const u16* xb  = xin  + (size_t)b * T * C;
    u16*       yb  = xout + (size_t)b * T * C;

    for (int it = 0; it < 4; ++it) {
        const int t0 = (blockIdx.x * 4 + it) * 128;
        f32x4 acc[2][4] = {};

#pragma unroll
        for (int tap = 0; tap < 2; ++tap) {
#pragma unroll
            for (int k0 = 0; k0 < 128; k0 += 32) {
                short8 af[2];
#pragma unroll
                for (int a = 0; a < 2; ++a) {
                    const int trow = t0 + wr * 32 + a * 16 + l15 - (tap ? 0 : d);
                    const int ch   = k0 + l4 * 8;
                    short8 v = {};
                    if (trow >= 0)
                        v = *reinterpret_cast<const short8*>(xb + (size_t)trow * C + ch);
                    af[a] = v;
                }
                const int koff = tap * 128 + k0 + l4 * 8;
#pragma unroll
                for (int j = 0; j < 4; ++j) {
                    const int o = wc * 64 + j * 16 + l15;
                    short8 bf = *reinterpret_cast<const short8*>(
                        &wlds[o * 256 + (koff ^ ((o & 7) << 3))]);
                    acc[0][j] = __builtin_amdgcn_mfma_f32_16x16x32_bf16(af[0], bf, acc[0][j], 0, 0, 0);
                    acc[1][j] = __builtin_amdgcn_mfma_f32_16x16x32_bf16(af[1], bf, acc[1][j], 0, 0, 0);
                }
            }
        }
        // epilogue: relu + cvt + u16 stores  (D: row=(l>>4)*4+r, col=l&15)
#pragma unroll
        for (int a = 0; a < 2; ++a) {
#pragma unroll
            for (int r = 0; r < 4; ++r) {
                const int t = t0 + wr * 32 + a * 16 + l4 * 4 + r;
#pragma unroll
                for (int j = 0; j < 4; ++j) {
                    const int o = wc * 64 + j * 16 + l15;
                    float y = acc[a][j][r];
                    y = y > 0.f ? y : 0.f;
                    yb[(size_t)t * C + o] = f2bf(y);
                }
            }
        }
    }
}

// ---------------------------------------------------------------------------
// Classifier: out[b][o][t] = sum_i Wc[o][i] x[b][t][i] + bias[o]   (f32 out)
// Block: 512 thr = 8 waves (4 t-quarters x 2 o-halves of 256). Tile 128t x 256o,
// 4 tiles per block (512 t-rows).
// ---------------------------------------------------------------------------
__global__ __launch_bounds__(512, 4) void cls_layer(
    const u16* __restrict__ xin, float* __restrict__ out,
    const u16* __restrict__ Wc, const float* __restrict__ bias)
{
    __shared__ u16 wlds[NCLS * C];  // 64 KiB
    const int tid = threadIdx.x;
    // 4096 chunks of 16B total (NCLS*C/8); 512 threads -> 8 iterations.
    // (round-4 bug: this was c<4, leaving o=128..255 weights unstaged)
#pragma unroll
    for (int c = 0; c < 8; ++c) {
        const int cc = c * 512 + tid;
        const int o = cc >> 4, kc = cc & 15;
        short8 v = *reinterpret_cast<const short8*>(Wc + o * C + kc * 8);
        *reinterpret_cast<short8*>(&wlds[o * C + ((kc * 8) ^ ((o & 7) << 3))]) = v;
    }
    __syncthreads();

    const int b   = blockIdx.y;
    const int wv  = tid >> 6, lane = tid & 63;
    const int wr  = wv >> 1, wc = wv & 1;
    const int l15 = lane & 15, l4 = lane >> 4;
    const u16* xb = xin + (size_t)b * T * C;
    float*     ob = out + (size_t)b * NCLS * T;

    for (int it = 0; it < 4; ++it) {
        const int t0 = (blockIdx.x * 4 + it) * 128;
        f32x4 acc[2][8] = {};

#pragma unroll
        for (int k0 = 0; k0 < 128; k0 += 32) {
            short8 af[2];
#pragma unroll
            for (int a = 0; a < 2; ++a) {
                const int trow = t0 + wr * 32 + a * 16 + l15;
                af[a] = *reinterpret_cast<const short8*>(xb + (size_t)trow * C + k0 + l4 * 8);
            }
            const int koff = k0 + l4 * 8;
#pragma unroll
            for (int j = 0; j < 8; ++j) {
                const int o = wc * 128 + j * 16 + l15;
                short8 bf = *reinterpret_cast<const short8*>(
                    &wlds[o * C + (koff ^ ((o & 7) << 3))]);
                acc[0][j] = __builtin_amdgcn_mfma_f32_16x16x32_bf16(af[0], bf, acc[0][j], 0, 0, 0);
                acc[1][j] = __builtin_amdgcn_mfma_f32_16x16x32_bf16(af[1], bf, acc[1][j], 0, 0, 0);
            }
        }
#pragma unroll
        for (int a = 0; a < 2; ++a) {
#pragma unroll
            for (int j = 0; j < 8; ++j) {
                const int o = wc * 128 + j * 16 + l15;
                const int t = t0 + wr * 32 + a * 16 + l4 * 4;
                const float bs = bias[o];
                f32x4 v = acc[a][j];
                float4 w = make_float4(v[0] + bs, v[1] + bs, v[2] + bs, v[3] + bs);
                *reinterpret_cast<float4*>(ob + (size_t)o * T + t) = w;
            }
        }
    }
}

// ---------------------------------------------------------------------------
extern "C" void kernel_launch(void* const* d_in, const int* in_sizes, int n_in,
                              void* d_out, int out_size, void* d_ws, size_t ws_size,
                              hipStream_t stream)
{
    const float* seq   = (const float*)d_in[0];
    const float* wf    = (const float*)d_in[1];
    const float* wrest = (const float*)d_in[2];
    const float* wcls  = (const float*)d_in[3];
    const float* bcls  = (const float*)d_in[4];
    float* out = (float*)d_out;

    const size_t xElems  = (size_t)BATCH * T * C;     // 32,768,000 bf16
    const size_t wtElems = (size_t)27 * 128 * 256;    // 884,736
    const size_t wcElems = (size_t)NCLS * C;          // 32,768

    u16 *xA, *xB, *Wt, *Wc;
    if (ws_size >= (2 * xElems + wtElems + wcElems + 1024) * sizeof(u16)) {
        // everything in workspace
        xA = (u16*)d_ws;
        xB = xA + xElems;
        Wt = xB + xElems;
    } else {
        // bufA lives in d_out scratch (65.5MB of 262MB); d_out is rewritten last
        xA = (u16*)d_out;
        xB = (u16*)d_ws;
        Wt = xB + xElems;
    }
    Wc = Wt + wtElems;

    prep_weights<<<dim3(896), dim3(256), 0, stream>>>(wrest, wcls, Wt, Wc);
    first_layer<<<dim3(T / 64, BATCH), dim3(256), 0, stream>>>(seq, xA, wf);

    u16* cur = xA;
    u16* nxt = xB;
    for (int i = 1; i < NLAYER; ++i) {
        const int d = 1 << ((i % 14) % 10);
        conv_layer<<<dim3(T / 512, BATCH), dim3(512), 0, stream>>>(
            cur, nxt, Wt + (size_t)(i - 1) * 128 * 256, d);
        u16* tmp = cur; cur = nxt; nxt = tmp;
    }
    // after 27 conv layers cur == xB (workspace) in both layouts
    cls_layer<<<dim3(T / 512, BATCH), dim3(512), 0, stream>>>(cur, out, Wc, bcls);
}

// Round 6
// 1470.291 us; speedup vs baseline: 1.8332x; 1.8332x over previous
//
#include <hip/hip_runtime.h>
#include <hip/hip_bf16.h>

#define BATCH 4
#define T 64000
#define C 128
#define NCLS 256
#define NLAYER 28

typedef __attribute__((ext_vector_type(8))) short short8;
typedef __attribute__((ext_vector_type(4))) float f32x4;
typedef unsigned short u16;

static __device__ __forceinline__ u16 f2bf(float x) {
    __hip_bfloat16 h = __float2bfloat16(x);
    return *reinterpret_cast<u16*>(&h);
}

// ---------------------------------------------------------------------------
// Weight prep: convert w_rest -> Wt[l][o][k] bf16 (k = tap*128 + i, tap0 = past)
// and w_cls -> Wc[o][k] bf16.
// ---------------------------------------------------------------------------
__global__ void prep_weights(const float* __restrict__ w_rest,
                             const float* __restrict__ w_cls,
                             u16* __restrict__ Wt, u16* __restrict__ Wc)
{
    const size_t n1 = (size_t)27 * 128 * 256;   // 884736
    const size_t n2 = (size_t)NCLS * C;         // 32768
    for (size_t idx = (size_t)blockIdx.x * 256 + threadIdx.x; idx < n1 + n2;
         idx += (size_t)gridDim.x * 256) {
        if (idx < n1) {
            const int k   = (int)(idx & 255);
            const int o   = (int)((idx >> 8) & 127);
            const int l   = (int)(idx >> 15);
            const int tap = k >> 7;
            const int i   = k & 127;
            Wt[idx] = f2bf(w_rest[(((size_t)l * 128 + o) * 128 + i) * 2 + tap]);
        } else {
            const size_t j = idx - n1;
            Wc[j] = f2bf(w_cls[j]);
        }
    }
}

// ---------------------------------------------------------------------------
// Layer 0: 1 channel -> 128 channels, d=1.  x[b][t][c] bf16 output.
// ---------------------------------------------------------------------------
__global__ void first_layer(const float* __restrict__ seq,
                            u16* __restrict__ xout,
                            const float* __restrict__ wf)
{
    __shared__ float w0[C], w1[C];
    const int tid = threadIdx.x;
    if (tid < C) { w0[tid] = wf[tid * 2]; w1[tid] = wf[tid * 2 + 1]; }
    __syncthreads();

    const int b  = blockIdx.y;
    const int og = tid & 15;
#pragma unroll
    for (int tt = 0; tt < 4; ++tt) {
        const int t = blockIdx.x * 64 + tt * 16 + (tid >> 4);
        const float s1 = seq[(size_t)b * T + t];
        const float s0 = (t > 0) ? seq[(size_t)b * T + t - 1] : 0.f;
        short8 v = {};
#pragma unroll
        for (int k = 0; k < 8; ++k) {
            const int o = og * 8 + k;
            float y = fmaf(w0[o], s0, w1[o] * s1);
            y = y > 0.f ? y : 0.f;
            v[k] = (short)f2bf(y);
        }
        *reinterpret_cast<short8*>(xout + ((size_t)b * T + t) * C + og * 8) = v;
    }
}

// ---------------------------------------------------------------------------
// Dilated conv layer (128->128, kernel 2, dilation d) as MFMA GEMM.
// D[t][o] = relu( sum_k A[t][k] * W[o][k] ),  k = tap*128 + ch, tap0 -> t-d.
// Block: 512 thr = 8 waves (4 t-quarters x 2 o-halves). Tile 128t x 128o,
// 4 tiles per block (512 t-rows).  Weights in LDS, XOR-swizzled.
// launch_bounds(512,2): VGPR cap 256 — round-5's (512,4) capped at 64 and
// spilled (FETCH +261MB of scratch reads). Body needs ~90 regs -> expect
// <=128 -> 4 waves/SIMD without spills.
// ---------------------------------------------------------------------------
__global__ __launch_bounds__(512, 2) void conv_layer(
    const u16* __restrict__ xin, u16* __restrict__ xout,
    const u16* __restrict__ Wt, int d)
{
    __shared__ u16 wlds[C * 256];   // 64 KiB
    const int tid = threadIdx.x;
#pragma unroll
    for (int c = 0; c < 8; ++c) {
        const int cc = c * 512 + tid;       // 4096 chunks of 16B
        const int o = cc >> 5, kc = cc & 31;
        short8 v = *reinterpret_cast<const short8*>(Wt + o * 256 + kc * 8);
        *reinterpret_cast<short8*>(&wlds[o * 256 + ((kc * 8) ^ ((o & 7) << 3))]) = v;
    }
    __syncthreads();

    const int b    = blockIdx.y;
    const int wv   = tid >> 6, lane = tid & 63;
    const int wr   = wv >> 1, wc = wv & 1;      // wr: t-quarter, wc: o-half
    const int l15  = lane & 15, l4 = lane >> 4;
    const u16* xb  = xin  + (size_t)b * T * C;
    u16*       yb  = xout + (size_t)b * T * C;

    for (int it = 0; it < 4; ++it) {
        const int t0 = (blockIdx.x * 4 + it) * 128;
        f32x4 acc[2][4] = {};

#pragma unroll
        for (int tap = 0; tap < 2; ++tap) {
#pragma unroll
            for (int k0 = 0; k0 < 128; k0 += 32) {
                short8 af[2];
#pragma unroll
                for (int a = 0; a < 2; ++a) {
                    const int trow = t0 + wr * 32 + a * 16 + l15 - (tap ? 0 : d);
                    const int ch   = k0 + l4 * 8;
                    short8 v = {};
                    if (trow >= 0)
                        v = *reinterpret_cast<const short8*>(xb + (size_t)trow * C + ch);
                    af[a] = v;
                }
                const int koff = tap * 128 + k0 + l4 * 8;
#pragma unroll
                for (int j = 0; j < 4; ++j) {
                    const int o = wc * 64 + j * 16 + l15;
                    short8 bf = *reinterpret_cast<const short8*>(
                        &wlds[o * 256 + (koff ^ ((o & 7) << 3))]);
                    acc[0][j] = __builtin_amdgcn_mfma_f32_16x16x32_bf16(af[0], bf, acc[0][j], 0, 0, 0);
                    acc[1][j] = __builtin_amdgcn_mfma_f32_16x16x32_bf16(af[1], bf, acc[1][j], 0, 0, 0);
                }
            }
        }
        // epilogue: relu + cvt + u16 stores  (D: row=(l>>4)*4+r, col=l&15)
#pragma unroll
        for (int a = 0; a < 2; ++a) {
#pragma unroll
            for (int r = 0; r < 4; ++r) {
                const int t = t0 + wr * 32 + a * 16 + l4 * 4 + r;
#pragma unroll
                for (int j = 0; j < 4; ++j) {
                    const int o = wc * 64 + j * 16 + l15;
                    float y = acc[a][j][r];
                    y = y > 0.f ? y : 0.f;
                    yb[(size_t)t * C + o] = f2bf(y);
                }
            }
        }
    }
}

// ---------------------------------------------------------------------------
// Classifier: out[b][o][t] = sum_i Wc[o][i] x[b][t][i] + bias[o]   (f32 out)
// Block: 512 thr = 8 waves as 2 t-halves x 4 o-quarters (acc[2][4]=32 regs —
// round-5's 4tx2o layout needed acc[2][8]=64 regs and spilled under the cap).
// Tile 64t x 256o, 8 tiles per block (512 t-rows).
// ---------------------------------------------------------------------------
__global__ __launch_bounds__(512, 2) void cls_layer(
    const u16* __restrict__ xin, float* __restrict__ out,
    const u16* __restrict__ Wc, const float* __restrict__ bias)
{
    __shared__ u16 wlds[NCLS * C];  // 64 KiB
    const int tid = threadIdx.x;
    // 4096 chunks of 16B total (NCLS*C/8); 512 threads -> 8 iterations.
#pragma unroll
    for (int c = 0; c < 8; ++c) {
        const int cc = c * 512 + tid;
        const int o = cc >> 4, kc = cc & 15;
        short8 v = *reinterpret_cast<const short8*>(Wc + o * C + kc * 8);
        *reinterpret_cast<short8*>(&wlds[o * C + ((kc * 8) ^ ((o & 7) << 3))]) = v;
    }
    __syncthreads();

    const int b   = blockIdx.y;
    const int wv  = tid >> 6, lane = tid & 63;
    const int wr  = wv >> 2, wc = wv & 3;       // wr: t-half, wc: o-quarter
    const int l15 = lane & 15, l4 = lane >> 4;
    const u16* xb = xin + (size_t)b * T * C;
    float*     ob = out + (size_t)b * NCLS * T;

    for (int it = 0; it < 8; ++it) {
        const int t0 = (blockIdx.x * 8 + it) * 64;
        f32x4 acc[2][4] = {};

#pragma unroll
        for (int k0 = 0; k0 < 128; k0 += 32) {
            short8 af[2];
#pragma unroll
            for (int a = 0; a < 2; ++a) {
                const int trow = t0 + wr * 32 + a * 16 + l15;
                af[a] = *reinterpret_cast<const short8*>(xb + (size_t)trow * C + k0 + l4 * 8);
            }
            const int koff = k0 + l4 * 8;
#pragma unroll
            for (int j = 0; j < 4; ++j) {
                const int o = wc * 64 + j * 16 + l15;
                short8 bf = *reinterpret_cast<const short8*>(
                    &wlds[o * C + (koff ^ ((o & 7) << 3))]);
                acc[0][j] = __builtin_amdgcn_mfma_f32_16x16x32_bf16(af[0], bf, acc[0][j], 0, 0, 0);
                acc[1][j] = __builtin_amdgcn_mfma_f32_16x16x32_bf16(af[1], bf, acc[1][j], 0, 0, 0);
            }
        }
#pragma unroll
        for (int a = 0; a < 2; ++a) {
#pragma unroll
            for (int j = 0; j < 4; ++j) {
                const int o = wc * 64 + j * 16 + l15;
                const int t = t0 + wr * 32 + a * 16 + l4 * 4;
                const float bs = bias[o];
                f32x4 v = acc[a][j];
                float4 w = make_float4(v[0] + bs, v[1] + bs, v[2] + bs, v[3] + bs);
                *reinterpret_cast<float4*>(ob + (size_t)o * T + t) = w;
            }
        }
    }
}

// ---------------------------------------------------------------------------
extern "C" void kernel_launch(void* const* d_in, const int* in_sizes, int n_in,
                              void* d_out, int out_size, void* d_ws, size_t ws_size,
                              hipStream_t stream)
{
    const float* seq   = (const float*)d_in[0];
    const float* wf    = (const float*)d_in[1];
    const float* wrest = (const float*)d_in[2];
    const float* wcls  = (const float*)d_in[3];
    const float* bcls  = (const float*)d_in[4];
    float* out = (float*)d_out;

    const size_t xElems  = (size_t)BATCH * T * C;     // 32,768,000 bf16
    const size_t wtElems = (size_t)27 * 128 * 256;    // 884,736
    const size_t wcElems = (size_t)NCLS * C;          // 32,768

    u16 *xA, *xB, *Wt, *Wc;
    if (ws_size >= (2 * xElems + wtElems + wcElems + 1024) * sizeof(u16)) {
        // everything in workspace
        xA = (u16*)d_ws;
        xB = xA + xElems;
        Wt = xB + xElems;
    } else {
        // bufA lives in d_out scratch (65.5MB of 262MB); d_out is rewritten last
        xA = (u16*)d_out;
        xB = (u16*)d_ws;
        Wt = xB + xElems;
    }
    Wc = Wt + wtElems;

    prep_weights<<<dim3(896), dim3(256), 0, stream>>>(wrest, wcls, Wt, Wc);
    first_layer<<<dim3(T / 64, BATCH), dim3(256), 0, stream>>>(seq, xA, wf);

    u16* cur = xA;
    u16* nxt = xB;
    for (int i = 1; i < NLAYER; ++i) {
        const int d = 1 << ((i % 14) % 10);
        conv_layer<<<dim3(T / 512, BATCH), dim3(512), 0, stream>>>(
            cur, nxt, Wt + (size_t)(i - 1) * 128 * 256, d);
        u16* tmp = cur; cur = nxt; nxt = tmp;
    }
    // after 27 conv layers cur == xB (workspace) in both layouts
    cls_layer<<<dim3(T / 512, BATCH), dim3(512), 0, stream>>>(cur, out, Wc, bcls);
}